// Round 2
// baseline (141.090 us; speedup 1.0000x reference)
//
#include <hip/hip_runtime.h>

#define NTREE  64
#define NFEAT  1024
#define NLEAF  64
#define NBATCH 32768
#define WAVES  4
#define THREADS 256
#define GRID   2048
#define WSTRIDE (GRID * WAVES)   // 8192 waves -> 4 rows each

// d[j] = sigmoid(x[b, fidx[t, j]]); layer k uses d[(2^k-1)+i] for parent i;
// child 2i *= d, child 2i+1 *= (1-d). prob = mu . pi[t]; probs[b][l][t] = mu[l].
__device__ __forceinline__ float sig1(float v) {
    return __builtin_amdgcn_rcpf(1.0f + __expf(-v));
}
__device__ __forceinline__ float4 sig4(float4 v) {
    return make_float4(sig1(v.x), sig1(v.y), sig1(v.z), sig1(v.w));
}

__global__ __launch_bounds__(THREADS, 4)
void forest_kernel(const float* __restrict__ x,
                   const int*   __restrict__ fidx,
                   const float* __restrict__ pi,
                   float* __restrict__ prob,    // [B][T]
                   float* __restrict__ probs)   // [B][L][T]
{
    __shared__ float          srow[WAVES][NFEAT];   // 16384 B (per-wave private row)
    __shared__ float          pil[NLEAF * NTREE];   // [l][t] transposed: 16384 B
    __shared__ unsigned short idxl[63 * 64];        // [c][t] byte offsets: 8064 B
                                                    // total 40832 B -> 4 blocks/CU

    const int tid  = threadIdx.x;
    const int wid  = tid >> 6;
    const int lane = tid & 63;      // lane == tree t

    // Stage fidx (as *4 byte-offsets, transposed [c][t]) and pi (transposed [l][t]).
    for (int i = tid; i < 63 * 64; i += THREADS) {
        int t = i / 63, c = i - t * 63;
        idxl[c * 64 + t] = (unsigned short)(fidx[i] << 2);
    }
    for (int i = tid; i < NTREE * NLEAF; i += THREADS) {
        int t = i >> 6, l = i & 63;
        pil[l * 64 + t] = pi[i];
    }
    __syncthreads();   // only cross-wave sync in the kernel

    const int t = lane;
    float* sw = &srow[wid][0];

    int b = blockIdx.x * WAVES + wid;
    // Prologue: load first row into registers.
    const float4* xr4 = reinterpret_cast<const float4*>(x + (size_t)b * NFEAT);
    float4 c0 = xr4[lane];
    float4 c1 = xr4[lane + 64];
    float4 c2 = xr4[lane + 128];
    float4 c3 = xr4[lane + 192];

    #pragma unroll 1
    for (int it = 0; it < NBATCH / WSTRIDE; ++it, b += WSTRIDE) {
        // ---- sigmoid current row -> this wave's LDS row ----
        float4* sr4 = reinterpret_cast<float4*>(sw);
        sr4[lane      ] = sig4(c0);
        sr4[lane +  64] = sig4(c1);
        sr4[lane + 128] = sig4(c2);
        sr4[lane + 192] = sig4(c3);

        // ---- prefetch next row (hides HBM latency under tree+stores) ----
        int bn = b + WSTRIDE;
        if (bn < NBATCH) {
            const float4* nx = reinterpret_cast<const float4*>(x + (size_t)bn * NFEAT);
            c0 = nx[lane];
            c1 = nx[lane + 64];
            c2 = nx[lane + 128];
            c3 = nx[lane + 192];
        }

        // ---- wave-local LDS fence: drain this wave's ds_writes (lockstep lanes,
        //      per-wave in-order DS => no s_barrier needed; srow is wave-private) ----
        asm volatile("s_waitcnt lgkmcnt(0)" ::: "memory");
        __builtin_amdgcn_sched_barrier(0);

        // ---- layers 0..4: in-place doubling, mu[0..31] ----
        float mu[32];
        mu[0] = 1.0f;
        #pragma unroll
        for (int k = 0; k < 5; ++k) {
            const int n = 1 << k;
            #pragma unroll
            for (int i = n - 1; i >= 0; --i) {
                float dv = *(const float*)((const char*)sw + idxl[(n - 1 + i) * 64 + t]);
                float m  = mu[i];
                float a  = m * dv;
                mu[2 * i]     = a;
                mu[2 * i + 1] = m - a;
            }
        }

        // ---- final layer fused with coalesced stores + pi-dot ----
        float acc = 0.0f;
        float* pb = probs + (size_t)b * (NLEAF * NTREE) + t;
        #pragma unroll
        for (int i = 0; i < 32; ++i) {
            float dv = *(const float*)((const char*)sw + idxl[(31 + i) * 64 + t]);
            float m  = mu[i];
            float a  = m * dv;            // leaf 2i
            float c  = m - a;             // leaf 2i+1
            pb[(2 * i) * NTREE]     = a;  // 64 lanes span t: 256B coalesced
            pb[(2 * i + 1) * NTREE] = c;
            acc = fmaf(a, pil[(2 * i) * 64 + t], acc);       // [l][t]: conflict-free
            acc = fmaf(c, pil[(2 * i + 1) * 64 + t], acc);
        }
        prob[b * NTREE + t] = acc;

        // WAR fence before next iteration overwrites srow (wave-local).
        asm volatile("s_waitcnt lgkmcnt(0)" ::: "memory");
    }
}

extern "C" void kernel_launch(void* const* d_in, const int* in_sizes, int n_in,
                              void* d_out, int out_size, void* d_ws, size_t ws_size,
                              hipStream_t stream) {
    const float* x    = (const float*)d_in[0];
    const int*   fidx = (const int*)d_in[1];
    const float* pi   = (const float*)d_in[2];
    float* prob  = (float*)d_out;                              // B*T
    float* probs = (float*)d_out + (size_t)NBATCH * NTREE;     // B*L*T

    dim3 grid(GRID), block(THREADS);
    hipLaunchKernelGGL(forest_kernel, grid, block, 0, stream,
                       x, fidx, pi, prob, probs);
}